// Round 1
// baseline (61.313 us; speedup 1.0000x reference)
//
#include <hip/hip_runtime.h>

#define BATCH 32
#define LATENT 128
#define NODE_DIM 8
#define MAX_NODES 512
#define H_NODE 128
#define H_EDGE 64
#define TILE 64
#define NTILE (MAX_NODES / TILE)            // 8
#define NUPPER (NTILE * (NTILE + 1) / 2)    // 36

// ---------------------------------------------------------------------------
// Kernel A: node generator.  h = relu(z@W1+b1); nodes = h@W2+b2.
// Grid (BATCH, 8): each block computes one batch's h (redundantly, cheap)
// and a 512-wide slice of the 4096 node outputs.
// ---------------------------------------------------------------------------
__global__ __launch_bounds__(128) void node_gen(
    const float* __restrict__ z,  const float* __restrict__ W1,
    const float* __restrict__ b1, const float* __restrict__ W2,
    const float* __restrict__ b2, float* __restrict__ nodes_out)
{
    const int b      = blockIdx.x;
    const int mslice = blockIdx.y;   // 0..7
    const int tid    = threadIdx.x;  // 0..127

    __shared__ float sz[LATENT];
    __shared__ float sh[H_NODE];

    sz[tid] = z[b * LATENT + tid];
    __syncthreads();

    // h[tid] — W1 column read coalesced across threads
    float acc = b1[tid];
#pragma unroll 8
    for (int k = 0; k < LATENT; ++k)
        acc += sz[k] * W1[k * H_NODE + tid];
    sh[tid] = fmaxf(acc, 0.0f);
    __syncthreads();

    // 512 outputs per block: m = mbase + tid + j*128, j=0..3
    const int mbase = mslice * 512;
    const int m0    = mbase + tid;
    float a4[4];
#pragma unroll
    for (int j = 0; j < 4; ++j) a4[j] = b2[m0 + j * 128];

    for (int k = 0; k < H_NODE; ++k) {
        const float hk = sh[k];
        const float* w = &W2[k * (MAX_NODES * NODE_DIM) + m0];
#pragma unroll
        for (int j = 0; j < 4; ++j) a4[j] += hk * w[j * 128];
    }
#pragma unroll
    for (int j = 0; j < 4; ++j)
        nodes_out[b * (MAX_NODES * NODE_DIM) + m0 + j * 128] = a4[j];
}

// ---------------------------------------------------------------------------
// Kernel B: edge generator + adjacency.
// Upper-triangular 64x64 tiles (incl. diagonal). Per tile:
//   U[i][c] = eb1[c] + sum_d nodes[i0+i][d]*E1[d][c]       (first half of concat)
//   V[j][c] =          sum_d nodes[j0+j][d]*E1[8+d][c]     (second half)
//   p(i,j)  = sigmoid( sum_c E2[c]*relu(U[i][c]+V[j][c]) + eb2 ),  i<j
// Write tile and its transpose (coalesced via LDS transpose).
// ---------------------------------------------------------------------------
__global__ __launch_bounds__(256) void edge_gen(
    const float* __restrict__ nodes, const float* __restrict__ E1,
    const float* __restrict__ eb1,   const float* __restrict__ E2,
    const float* __restrict__ eb2,   float* __restrict__ adj)
{
    const int b = blockIdx.y;
    int rem = blockIdx.x;            // 0..35 -> (bi, bj) with bi <= bj
    int bi = 0;
    while (rem >= NTILE - bi) { rem -= NTILE - bi; ++bi; }
    const int bj = bi + rem;

    const int tid = threadIdx.x;     // 0..255
    const int lane = tid & 63;       // ti within tile
    const int wv   = tid >> 6;       // wave 0..3
    const int tjb  = wv * 16;        // this wave's tj block

    __shared__ float U[TILE][H_EDGE + 1];     // +1 pad: 2-way bank alias only
    __shared__ float V[TILE][H_EDGE + 1];
    __shared__ float P[TILE][TILE + 1];
    __shared__ float sNi[TILE][NODE_DIM];
    __shared__ float sNj[TILE][NODE_DIM];
    __shared__ float sE1[2 * NODE_DIM][H_EDGE];
    __shared__ float sE2[H_EDGE];
    __shared__ float sEb1[H_EDGE];

    // ---- stage constants + node rows ----
    for (int idx = tid; idx < 2 * NODE_DIM * H_EDGE; idx += 256)
        sE1[idx >> 6][idx & 63] = E1[idx];
    if (tid < H_EDGE) { sE2[tid] = E2[tid]; sEb1[tid] = eb1[tid]; }

    const float* nb = nodes + (size_t)b * MAX_NODES * NODE_DIM;
    for (int idx = tid; idx < TILE * NODE_DIM; idx += 256) {
        (&sNi[0][0])[idx] = nb[bi * TILE * NODE_DIM + idx];
        (&sNj[0][0])[idx] = nb[bj * TILE * NODE_DIM + idx];
    }
    __syncthreads();

    // ---- U, V: 64x64 each, 16 entries/thread, 8 FMA each ----
    for (int idx = tid; idx < TILE * H_EDGE; idx += 256) {
        const int i = idx >> 6, c = idx & 63;
        float au = sEb1[c], av = 0.0f;
#pragma unroll
        for (int d = 0; d < NODE_DIM; ++d) {
            au += sNi[i][d] * sE1[d][c];
            av += sNj[i][d] * sE1[NODE_DIM + d][c];
        }
        U[i][c] = au;
        V[i][c] = av;
    }
    __syncthreads();

    // ---- main compute: lane = ti, each thread does 16 tj ----
    float acc[16];
#pragma unroll
    for (int j = 0; j < 16; ++j) acc[j] = 0.0f;

#pragma unroll 4
    for (int c = 0; c < H_EDGE; ++c) {
        const float u = U[lane][c];   // per-lane, pad -> conflict-free
        const float w = sE2[c];       // broadcast
#pragma unroll
        for (int j = 0; j < 16; ++j) {
            const float s = u + V[tjb + j][c];   // broadcast
            acc[j] += w * fmaxf(s, 0.0f);
        }
    }

    const float bias = eb2[0];
#pragma unroll
    for (int j = 0; j < 16; ++j) {
        const float x = acc[j] + bias;
        P[lane][tjb + j] = 1.0f / (1.0f + __expf(-x));
    }
    __syncthreads();

    // ---- write adj (and mirror) ----
    float* adjb = adj + (size_t)b * MAX_NODES * MAX_NODES;
    if (bi == bj) {
        for (int idx = tid; idx < TILE * TILE; idx += 256) {
            const int r = idx >> 6, c = idx & 63;
            const float v = (r < c) ? P[r][c] : (r > c ? P[c][r] : 0.0f);
            adjb[(size_t)(bi * TILE + r) * MAX_NODES + bi * TILE + c] = v;
        }
    } else {
        for (int idx = tid; idx < TILE * TILE; idx += 256) {
            const int r = idx >> 6, c = idx & 63;
            adjb[(size_t)(bi * TILE + r) * MAX_NODES + bj * TILE + c] = P[r][c];
            adjb[(size_t)(bj * TILE + r) * MAX_NODES + bi * TILE + c] = P[c][r];
        }
    }
}

// ---------------------------------------------------------------------------
extern "C" void kernel_launch(void* const* d_in, const int* in_sizes, int n_in,
                              void* d_out, int out_size, void* d_ws, size_t ws_size,
                              hipStream_t stream)
{
    const float* z   = (const float*)d_in[0];
    const float* W1  = (const float*)d_in[1];
    const float* b1  = (const float*)d_in[2];
    const float* W2  = (const float*)d_in[3];
    const float* b2  = (const float*)d_in[4];
    const float* E1  = (const float*)d_in[5];
    const float* eb1 = (const float*)d_in[6];
    const float* E2  = (const float*)d_in[7];
    const float* eb2 = (const float*)d_in[8];

    float* nodes_out = (float*)d_out;                                   // [32,512,8]
    float* adj       = (float*)d_out + BATCH * MAX_NODES * NODE_DIM;    // [32,512,512]

    dim3 gA(BATCH, 8);
    node_gen<<<gA, 128, 0, stream>>>(z, W1, b1, W2, b2, nodes_out);

    dim3 gB(NUPPER, BATCH);
    edge_gen<<<gB, 256, 0, stream>>>(nodes_out, E1, eb1, E2, eb2, adj);
}